// Round 4
// baseline (501.076 us; speedup 1.0000x reference)
//
#include <hip/hip_runtime.h>
#include <hip/hip_bf16.h>

// Local-window attention, B=32 S=1024(16x64) H=8 D=384/8=48, window 7x11.
// R4: fix R3's out-of-range XOR swizzle — pad LDS row stride to 64 floats
//     (16 float4-slots) so slot^swz (<=15) stays in-row. Same 4-wave structure.
//     GEMM/cvt kernels unchanged from R2 (passing).

typedef __attribute__((ext_vector_type(8))) unsigned short ushort8;
typedef __attribute__((ext_vector_type(4))) unsigned short ushort4v;
typedef __attribute__((ext_vector_type(8))) short short8v;
typedef __attribute__((ext_vector_type(4))) float floatx4;

__device__ __forceinline__ float bf2f(unsigned short u) {
  union { unsigned int i; float f; } x;
  x.i = ((unsigned int)u) << 16;
  return x.f;
}

__device__ __forceinline__ unsigned short f2bu(float f) {
  union { float f; unsigned int i; } x;
  x.f = f;
  unsigned int lsb = (x.i >> 16) & 1u;
  x.i += 0x7FFFu + lsb;  // RNE
  return (unsigned short)(x.i >> 16);
}

__device__ __forceinline__ void gload_lds16(const void* g, void* l) {
  __builtin_amdgcn_global_load_lds(
      (const __attribute__((address_space(1))) unsigned int*)g,
      (__attribute__((address_space(3))) unsigned int*)l, 16, 0, 0);
}

// ---------------- K0a: f32 -> bf16 ----------------
__global__ __launch_bounds__(256) void cvt_f32_bf16(
    const float4* __restrict__ in, ushort4v* __restrict__ out, int n4) {
  const int i = blockIdx.x * 256 + threadIdx.x;
  if (i < n4) {
    const float4 v = in[i];
    ushort4v o;
    o[0] = f2bu(v.x); o[1] = f2bu(v.y); o[2] = f2bu(v.z); o[3] = f2bu(v.w);
    out[i] = o;
  }
}

// ---------------- K0b/c: transpose f32 [R][C] -> bf16 [C][R] ----------------
__global__ __launch_bounds__(256) void transpose_cvt(
    const float* __restrict__ in, unsigned short* __restrict__ out, int R, int C) {
  __shared__ float t[32][33];
  const int c0 = blockIdx.x * 32, r0 = blockIdx.y * 32;
  const int tx = threadIdx.x, ty = threadIdx.y;
  #pragma unroll
  for (int rr = ty; rr < 32; rr += 8) t[rr][tx] = in[(size_t)(r0 + rr) * C + c0 + tx];
  __syncthreads();
  #pragma unroll
  for (int rr = ty; rr < 32; rr += 8)
    out[(size_t)(c0 + rr) * R + r0 + tx] = f2bu(t[tx][rr]);
}

// ---------------- MFMA GEMM (unchanged from R2) ----------------
template <int MODE>
__global__ __launch_bounds__(256, 2) void gemm_mfma(
    const unsigned short* __restrict__ A,   // [M][384] bf16
    const unsigned short* __restrict__ Bt,  // [N][384] bf16 (= B^T)
    const float* __restrict__ bias, float* __restrict__ outf,
    unsigned short* __restrict__ qws, unsigned short* __restrict__ kws,
    unsigned short* __restrict__ vws)
{
  __shared__ unsigned short As[128 * 32];
  __shared__ unsigned short Bs[128 * 32];
  const int tid = threadIdx.x;
  const int lane = tid & 63, w = tid >> 6;
  const int wm = w & 1, wn = w >> 1;
  const int n0 = blockIdx.x * 128;
  const int m0 = blockIdx.y * 128;

  floatx4 acc[4][4];
  #pragma unroll
  for (int mi = 0; mi < 4; ++mi)
    #pragma unroll
    for (int ni = 0; ni < 4; ++ni)
      acc[mi][ni] = (floatx4){0.f, 0.f, 0.f, 0.f};

  const int srow = w * 16 + (lane >> 2);
  const int kslot16 = (lane & 3) * 16;

  for (int k0 = 0; k0 < 384; k0 += 32) {
    __syncthreads();
    #pragma unroll
    for (int c = 0; c < 2; ++c) {
      const int r = c * 64 + srow;
      const int kb = kslot16 ^ ((r & 3) << 4);
      gload_lds16((const char*)A + (size_t)(m0 + r) * 768 + k0 * 2 + kb,
                  (char*)As + c * 4096 + w * 1024);
      gload_lds16((const char*)Bt + (size_t)(n0 + r) * 768 + k0 * 2 + kb,
                  (char*)Bs + c * 4096 + w * 1024);
    }
    __syncthreads();

    short8v a[4], b[4];
    const int kgb = (lane >> 4) * 16;
    #pragma unroll
    for (int mi = 0; mi < 4; ++mi) {
      const int r = wm * 64 + mi * 16 + (lane & 15);
      a[mi] = *reinterpret_cast<const short8v*>(
          (const char*)As + r * 64 + (kgb ^ ((r & 3) << 4)));
    }
    #pragma unroll
    for (int ni = 0; ni < 4; ++ni) {
      const int r = wn * 64 + ni * 16 + (lane & 15);
      b[ni] = *reinterpret_cast<const short8v*>(
          (const char*)Bs + r * 64 + (kgb ^ ((r & 3) << 4)));
    }
    #pragma unroll
    for (int mi = 0; mi < 4; ++mi)
      #pragma unroll
      for (int ni = 0; ni < 4; ++ni)
        acc[mi][ni] = __builtin_amdgcn_mfma_f32_16x16x32_bf16(
            a[mi], b[ni], acc[mi][ni], 0, 0, 0);
  }

  const int col_l = lane & 15;
  const int row_l = (lane >> 4) * 4;

  if (MODE == 0) {
    const float QSCALE = 0.14433756729740643f;  // 1/sqrt(48)
    #pragma unroll
    for (int ni = 0; ni < 4; ++ni) {
      const int cg = n0 + wn * 64 + ni * 16 + col_l;
      const int which = cg / 384;
      const int rem = cg - which * 384;
      const int h = rem / 48;
      const int d = rem - h * 48;
      unsigned short* dst = (which == 0) ? qws : (which == 1) ? kws : vws;
      const float scale = (which == 0) ? QSCALE : 1.f;
      #pragma unroll
      for (int mi = 0; mi < 4; ++mi) {
        #pragma unroll
        for (int reg = 0; reg < 4; ++reg) {
          const int r = m0 + wm * 64 + mi * 16 + row_l + reg;
          const int bb = r >> 10, s = r & 1023;
          dst[(((size_t)(bb * 8 + h)) * 1024 + s) * 48 + d] =
              f2bu(acc[mi][ni][reg] * scale);
        }
      }
    }
  } else {
    #pragma unroll
    for (int ni = 0; ni < 4; ++ni) {
      const int cg = n0 + wn * 64 + ni * 16 + col_l;
      const float bv = bias[cg];
      #pragma unroll
      for (int mi = 0; mi < 4; ++mi) {
        #pragma unroll
        for (int reg = 0; reg < 4; ++reg) {
          const int r = m0 + wm * 64 + mi * 16 + row_l + reg;
          outf[(size_t)r * 384 + cg] = acc[mi][ni][reg] + bv;
        }
      }
    }
  }
}

// ---------------- K2: local attention, 4 waves/block ----------------
// grid = B*H*4 blocks of 256. Wave w handles image row i0+w (i0 = 4*(blk&3)).
// One shared K/V f32 staging buffer swept over ki in [i0-3, i0+6] (clipped);
// wave w consumes ki in [i0+w-3, i0+w+3] (clipped).
// LDS layout: row stride 64 floats (16 float4-slots; data in slots 0..11 pre-
// swizzle), slot XOR swizzle: addr(row,slot) = row*64 + ((slot ^ ((row>>1)&7))<<2)
// slot<=11, swz<=7 -> slot^swz<=15: IN-RANGE (R3 bug: stride was 12 slots).
// Bank check: row base = 256B = bank 0 for all rows; swz spreads fixed-u reads
// across all 8 four-bank groups per 16 consecutive rows -> wave64 b128 at the
// 8-cycle floor. Same swizzle on write & read.
__global__ __launch_bounds__(256) void attn_local(
    const unsigned short* __restrict__ qws,
    const unsigned short* __restrict__ kws,
    const unsigned short* __restrict__ vws,
    unsigned short* __restrict__ attn_out)  // [B*S, 384] bf16
{
  __shared__ float ksm[64 * 64];
  __shared__ float vsm[64 * 64];

  const int blk = blockIdx.x;
  const int i0 = (blk & 3) * 4;
  const int h = (blk >> 2) & 7;
  const int b = blk >> 5;
  const int tid = threadIdx.x;
  const int w = tid >> 6;
  const int j = tid & 63;           // query column / staging row
  const int i = i0 + w;             // this wave's image row
  const size_t bh = ((size_t)b * 8 + h) * 1024;

  // q into registers (48 f32), already scaled by 1/sqrt(D) in K1
  float q[48];
  {
    const ushort8* qp = reinterpret_cast<const ushort8*>(qws + (bh + (size_t)i * 64 + j) * 48);
    #pragma unroll
    for (int u = 0; u < 6; ++u) {
      const ushort8 t = qp[u];
      #pragma unroll
      for (int ww = 0; ww < 8; ++ww) q[u * 8 + ww] = bf2f(t[ww]);
    }
  }

  float m = -INFINITY, l = 0.f;
  float o[48];
  #pragma unroll
  for (int d = 0; d < 48; ++d) o[d] = 0.f;

  const int kstart = (i0 - 3 < 0) ? 0 : i0 - 3;
  const int kend   = (i0 + 6 > 15) ? 15 : i0 + 6;
  const int wlo = (i - 3 < 0) ? 0 : i - 3;
  const int whi = (i + 3 > 15) ? 15 : i + 3;

  // staging: flat chunk c in [0,768): tensor = c>=384; row = (c%384)/6;
  // chunk-in-row = c%6 (16B = 8 dims = 2 slots)
  for (int ki = kstart; ki <= kend; ++ki) {
    #pragma unroll
    for (int cq = 0; cq < 3; ++cq) {
      const int c = tid + cq * 256;
      const int tensor = c >= 384;
      const int cr = tensor ? c - 384 : c;
      const int row = cr / 6;
      const int cir = cr - row * 6;
      const int d0 = cir * 8;
      const unsigned short* src = (tensor ? vws : kws) + (bh + (size_t)ki * 64 + row) * 48 + d0;
      const ushort8 t = *reinterpret_cast<const ushort8*>(src);
      float* dstbuf = tensor ? vsm : ksm;
      const int swz = (row >> 1) & 7;
      const int s0 = cir * 2;
      *reinterpret_cast<float4*>(&dstbuf[row * 64 + (((s0)     ^ swz) << 2)]) =
          make_float4(bf2f(t[0]), bf2f(t[1]), bf2f(t[2]), bf2f(t[3]));
      *reinterpret_cast<float4*>(&dstbuf[row * 64 + (((s0 + 1) ^ swz) << 2)]) =
          make_float4(bf2f(t[4]), bf2f(t[5]), bf2f(t[6]), bf2f(t[7]));
    }
    __syncthreads();

    if (ki >= wlo && ki <= whi) {
      float sc[11];
      float rowmax = -INFINITY;
      #pragma unroll
      for (int n = 0; n < 11; ++n) {
        const int kj = j - 5 + n;
        const bool valid = ((unsigned)kj < 64u);
        const int kjc = valid ? kj : j;
        const float* kr = &ksm[kjc * 64];
        const int swz = (kjc >> 1) & 7;
        float accd = 0.f;
        #pragma unroll
        for (int u = 0; u < 12; ++u) {
          const float4 kv = *reinterpret_cast<const float4*>(kr + ((u ^ swz) << 2));
          accd = fmaf(q[4 * u + 0], kv.x, accd);
          accd = fmaf(q[4 * u + 1], kv.y, accd);
          accd = fmaf(q[4 * u + 2], kv.z, accd);
          accd = fmaf(q[4 * u + 3], kv.w, accd);
        }
        sc[n] = valid ? accd : -INFINITY;
        rowmax = fmaxf(rowmax, sc[n]);
      }

      const float mnew = fmaxf(m, rowmax);
      const float corr = __expf(m - mnew);
      float p[11], psum = 0.f;
      #pragma unroll
      for (int n = 0; n < 11; ++n) { p[n] = __expf(sc[n] - mnew); psum += p[n]; }
      l = l * corr + psum;
      m = mnew;
      #pragma unroll
      for (int d = 0; d < 48; ++d) o[d] *= corr;
      #pragma unroll
      for (int n = 0; n < 11; ++n) {
        const int kj = j - 5 + n;
        const int kjc = ((unsigned)kj < 64u) ? kj : j;  // p[n]==0 when clamped
        const float pn = p[n];
        const float* vr = &vsm[kjc * 64];
        const int swz = (kjc >> 1) & 7;
        #pragma unroll
        for (int u = 0; u < 12; ++u) {
          const float4 vv = *reinterpret_cast<const float4*>(vr + ((u ^ swz) << 2));
          o[4 * u + 0] = fmaf(pn, vv.x, o[4 * u + 0]);
          o[4 * u + 1] = fmaf(pn, vv.y, o[4 * u + 1]);
          o[4 * u + 2] = fmaf(pn, vv.z, o[4 * u + 2]);
          o[4 * u + 3] = fmaf(pn, vv.w, o[4 * u + 3]);
        }
      }
    }
    __syncthreads();  // before next stage overwrites
  }

  const float inv = 1.0f / l;
  unsigned short* op = attn_out + ((size_t)b * 1024 + (size_t)i * 64 + j) * 384 + h * 48;
  #pragma unroll
  for (int u = 0; u < 6; ++u) {
    ushort8 pk;
    #pragma unroll
    for (int w2 = 0; w2 < 8; ++w2) pk[w2] = f2bu(o[u * 8 + w2] * inv);
    *reinterpret_cast<ushort8*>(op + u * 8) = pk;
  }
}

extern "C" void kernel_launch(void* const* d_in, const int* in_sizes, int n_in,
                              void* d_out, int out_size, void* d_ws, size_t ws_size,
                              hipStream_t stream) {
  const float* x      = (const float*)d_in[0];
  const float* w_qkv  = (const float*)d_in[1];
  const float* w_proj = (const float*)d_in[2];
  const float* b_proj = (const float*)d_in[3];
  // d_in[4] (mask) unused: window is analytic (|di|<=3, |dj|<=5)

  const size_t T = 25165824;  // 32768*384*2 bytes
  char* ws = (char*)d_ws;
  unsigned short* xb    = (unsigned short*)ws;            // aliased with attn_out
  unsigned short* qws   = (unsigned short*)(ws + T);
  unsigned short* kws   = (unsigned short*)(ws + 2 * T);
  unsigned short* vws   = (unsigned short*)(ws + 3 * T);
  unsigned short* wqkvT = (unsigned short*)(ws + 4 * T);
  unsigned short* wpT   = (unsigned short*)(ws + 4 * T + 884736);
  unsigned short* attn_out = xb;  // xb dead after K1
  float* out = (float*)d_out;

  // K0: conversions
  cvt_f32_bf16<<<12288, 256, 0, stream>>>((const float4*)x, (ushort4v*)xb, 3145728);
  transpose_cvt<<<dim3(36, 12), dim3(32, 8), 0, stream>>>(w_qkv, wqkvT, 384, 1152);
  transpose_cvt<<<dim3(12, 12), dim3(32, 8), 0, stream>>>(w_proj, wpT, 384, 384);

  // K1: qkv GEMM (M=32768, K=384, N=1152) -> scatter bf16 [B,H,S,D]
  gemm_mfma<0><<<dim3(9, 256), 256, 0, stream>>>(xb, wqkvT, nullptr, nullptr,
                                                 qws, kws, vws);
  // K2: local attention -> attn_out bf16 [B*S, 384]
  attn_local<<<dim3(1024), 256, 0, stream>>>(qws, kws, vws, attn_out);
  // K3: out = attn_out @ w_proj + bias (N=384), f32 out
  gemm_mfma<1><<<dim3(3, 256), 256, 0, stream>>>(attn_out, wpT, b_proj, out,
                                                 nullptr, nullptr, nullptr);
}

// Round 6
// 197.188 us; speedup vs baseline: 2.5411x; 2.5411x over previous
//
#include <hip/hip_runtime.h>
#include <hip/hip_bf16.h>

// Local-window attention, B=32 S=1024(16x64) H=8 D=384/8=48, window 7x11.
// R6: fix R5's NaN — softmax stats for query q are spread across the 4 lanes
//     ql+16g (each holds k-residues 4g..4g+3 mod 16). Reduce m (max) and psum
//     (sum) across the g-group via __shfl_xor 16/32 before exp/normalize.
//     (R5 bug: lane-local m could be -inf when the lane's whole residue class
//      fell outside the 11-wide window -> exp(-inf - -inf) = NaN; and P used
//      inconsistent maxima across g-groups.)
//     Everything else unchanged from R5 (GEMMs = R2-verified).

typedef __attribute__((ext_vector_type(8))) unsigned short ushort8;
typedef __attribute__((ext_vector_type(4))) unsigned short ushort4v;
typedef __attribute__((ext_vector_type(8))) short short8v;
typedef __attribute__((ext_vector_type(4))) float floatx4;

__device__ __forceinline__ float bf2f(unsigned short u) {
  union { unsigned int i; float f; } x;
  x.i = ((unsigned int)u) << 16;
  return x.f;
}

__device__ __forceinline__ unsigned short f2bu(float f) {
  union { float f; unsigned int i; } x;
  x.f = f;
  unsigned int lsb = (x.i >> 16) & 1u;
  x.i += 0x7FFFu + lsb;  // RNE
  return (unsigned short)(x.i >> 16);
}

__device__ __forceinline__ void gload_lds16(const void* g, void* l) {
  __builtin_amdgcn_global_load_lds(
      (const __attribute__((address_space(1))) unsigned int*)g,
      (__attribute__((address_space(3))) unsigned int*)l, 16, 0, 0);
}

// ---------------- K0a: f32 -> bf16 ----------------
__global__ __launch_bounds__(256) void cvt_f32_bf16(
    const float4* __restrict__ in, ushort4v* __restrict__ out, int n4) {
  const int i = blockIdx.x * 256 + threadIdx.x;
  if (i < n4) {
    const float4 v = in[i];
    ushort4v o;
    o[0] = f2bu(v.x); o[1] = f2bu(v.y); o[2] = f2bu(v.z); o[3] = f2bu(v.w);
    out[i] = o;
  }
}

// ---------------- K0b/c: transpose f32 [R][C] -> bf16 [C][R] ----------------
__global__ __launch_bounds__(256) void transpose_cvt(
    const float* __restrict__ in, unsigned short* __restrict__ out, int R, int C) {
  __shared__ float t[32][33];
  const int c0 = blockIdx.x * 32, r0 = blockIdx.y * 32;
  const int tx = threadIdx.x, ty = threadIdx.y;
  #pragma unroll
  for (int rr = ty; rr < 32; rr += 8) t[rr][tx] = in[(size_t)(r0 + rr) * C + c0 + tx];
  __syncthreads();
  #pragma unroll
  for (int rr = ty; rr < 32; rr += 8)
    out[(size_t)(c0 + rr) * R + r0 + tx] = f2bu(t[tx][rr]);
}

// ---------------- MFMA GEMM (R2-verified; MODE 0 writes V transposed) ----
template <int MODE>
__global__ __launch_bounds__(256, 2) void gemm_mfma(
    const unsigned short* __restrict__ A,   // [M][384] bf16
    const unsigned short* __restrict__ Bt,  // [N][384] bf16 (= B^T)
    const float* __restrict__ bias, float* __restrict__ outf,
    unsigned short* __restrict__ qws, unsigned short* __restrict__ kws,
    unsigned short* __restrict__ vtws)
{
  __shared__ unsigned short As[128 * 32];
  __shared__ unsigned short Bs[128 * 32];
  const int tid = threadIdx.x;
  const int lane = tid & 63, w = tid >> 6;
  const int wm = w & 1, wn = w >> 1;
  const int n0 = blockIdx.x * 128;
  const int m0 = blockIdx.y * 128;

  floatx4 acc[4][4];
  #pragma unroll
  for (int mi = 0; mi < 4; ++mi)
    #pragma unroll
    for (int ni = 0; ni < 4; ++ni)
      acc[mi][ni] = (floatx4){0.f, 0.f, 0.f, 0.f};

  const int srow = w * 16 + (lane >> 2);
  const int kslot16 = (lane & 3) * 16;

  for (int k0 = 0; k0 < 384; k0 += 32) {
    __syncthreads();
    #pragma unroll
    for (int c = 0; c < 2; ++c) {
      const int r = c * 64 + srow;
      const int kb = kslot16 ^ ((r & 3) << 4);
      gload_lds16((const char*)A + (size_t)(m0 + r) * 768 + k0 * 2 + kb,
                  (char*)As + c * 4096 + w * 1024);
      gload_lds16((const char*)Bt + (size_t)(n0 + r) * 768 + k0 * 2 + kb,
                  (char*)Bs + c * 4096 + w * 1024);
    }
    __syncthreads();

    short8v a[4], b[4];
    const int kgb = (lane >> 4) * 16;
    #pragma unroll
    for (int mi = 0; mi < 4; ++mi) {
      const int r = wm * 64 + mi * 16 + (lane & 15);
      a[mi] = *reinterpret_cast<const short8v*>(
          (const char*)As + r * 64 + (kgb ^ ((r & 3) << 4)));
    }
    #pragma unroll
    for (int ni = 0; ni < 4; ++ni) {
      const int r = wn * 64 + ni * 16 + (lane & 15);
      b[ni] = *reinterpret_cast<const short8v*>(
          (const char*)Bs + r * 64 + (kgb ^ ((r & 3) << 4)));
    }
    #pragma unroll
    for (int mi = 0; mi < 4; ++mi)
      #pragma unroll
      for (int ni = 0; ni < 4; ++ni)
        acc[mi][ni] = __builtin_amdgcn_mfma_f32_16x16x32_bf16(
            a[mi], b[ni], acc[mi][ni], 0, 0, 0);
  }

  const int col_l = lane & 15;
  const int row_l = (lane >> 4) * 4;

  if (MODE == 0) {
    const float QSCALE = 0.14433756729740643f;  // 1/sqrt(48)
    #pragma unroll
    for (int ni = 0; ni < 4; ++ni) {
      const int cg = n0 + wn * 64 + ni * 16 + col_l;
      const int which = cg / 384;
      const int rem = cg - which * 384;
      const int h = rem / 48;
      const int d = rem - h * 48;
      const float scale = (which == 0) ? QSCALE : 1.f;
      #pragma unroll
      for (int mi = 0; mi < 4; ++mi) {
        #pragma unroll
        for (int reg = 0; reg < 4; ++reg) {
          const int r = m0 + wm * 64 + mi * 16 + row_l + reg;
          const int bb = r >> 10, s = r & 1023;
          const unsigned short val = f2bu(acc[mi][ni][reg] * scale);
          if (which == 0)
            qws[(((size_t)(bb * 8 + h)) * 1024 + s) * 48 + d] = val;
          else if (which == 1)
            kws[(((size_t)(bb * 8 + h)) * 1024 + s) * 48 + d] = val;
          else  // V stored TRANSPOSED: vt[bh][d][s]
            vtws[(((size_t)(bb * 8 + h)) * 48 + d) * 1024 + s] = val;
        }
      }
    }
  } else {
    #pragma unroll
    for (int ni = 0; ni < 4; ++ni) {
      const int cg = n0 + wn * 64 + ni * 16 + col_l;
      const float bv = bias[cg];
      #pragma unroll
      for (int mi = 0; mi < 4; ++mi) {
        #pragma unroll
        for (int reg = 0; reg < 4; ++reg) {
          const int r = m0 + wm * 64 + mi * 16 + row_l + reg;
          outf[(size_t)r * 384 + cg] = acc[mi][ni][reg] + bv;
        }
      }
    }
  }
}

// ---------------- K2: MFMA local attention ----------------
// 1 wave per task (b,h,i). S^T = K·Q^T per (ktile,qtile); lane (ql,g) holds
// S^T[k=16kt+4g+r][q=16qt+ql]. Softmax stats reduced across the g-group
// (shfl_xor 16/32) so all 64 k-scores of a q share one max & sum. P goes
// through LDS [64q][72k] bf16 (C-layout write, B-frag read). O^T = V^T·P^T.
__global__ __launch_bounds__(64) void attn_mfma(
    const unsigned short* __restrict__ qws,  // [bh][1024][48]
    const unsigned short* __restrict__ kws,  // [bh][1024][48]
    const unsigned short* __restrict__ vt,   // [bh][48][1024]
    unsigned short* __restrict__ attn_out)   // [b*1024][384] bf16
{
  __shared__ unsigned short plds[64 * 72];  // stride 144B: 16B-aligned rows

  const int task = ((blockIdx.x & 7) << 9) | (blockIdx.x >> 3);  // 4096%8==0
  const int i  = task & 15;
  const int bh = task >> 4;
  const int lane = threadIdx.x;
  const int ql = lane & 15;   // q local (also A-frag row local)
  const int g  = lane >> 4;   // 8-elem k-slice group

  const unsigned short* qbase = qws + (size_t)bh * 1024 * 48;
  const unsigned short* kbase = kws + (size_t)bh * 1024 * 48;
  const unsigned short* vbase = vt  + (size_t)bh * 48 * 1024;

  const short8v zfrag = (short8v){0, 0, 0, 0, 0, 0, 0, 0};

  // Q fragments [qt][kstep]; D=48 zero-padded to 64 (kstep1, g>=2 -> 0)
  short8v qf[4][2];
  #pragma unroll
  for (int qt = 0; qt < 4; ++qt) {
    const unsigned short* qrow = qbase + (size_t)(i * 64 + qt * 16 + ql) * 48;
    qf[qt][0] = *reinterpret_cast<const short8v*>(qrow + 8 * g);
    qf[qt][1] = (g < 2) ? *reinterpret_cast<const short8v*>(qrow + 32 + 8 * g)
                        : zfrag;
  }

  floatx4 ot[3][4];  // O^T accum [dtile][qtile], d = 16dt+4g+reg, q = qt*16+ql
  #pragma unroll
  for (int dt = 0; dt < 3; ++dt)
    #pragma unroll
    for (int qt = 0; qt < 4; ++qt)
      ot[dt][qt] = (floatx4){0.f, 0.f, 0.f, 0.f};
  float mreg[4] = {-INFINITY, -INFINITY, -INFINITY, -INFINITY};
  float lreg[4] = {0.f, 0.f, 0.f, 0.f};

  const int ki0 = (i - 3 < 0) ? 0 : i - 3;
  const int ki1 = (i + 3 > 15) ? 15 : i + 3;

  for (int ki = ki0; ki <= ki1; ++ki) {
    // K fragments [kt][kstep]
    short8v kf[4][2];
    #pragma unroll
    for (int kt = 0; kt < 4; ++kt) {
      const unsigned short* krow = kbase + (size_t)(ki * 64 + kt * 16 + ql) * 48;
      kf[kt][0] = *reinterpret_cast<const short8v*>(krow + 8 * g);
      kf[kt][1] = (g < 2) ? *reinterpret_cast<const short8v*>(krow + 32 + 8 * g)
                          : zfrag;
    }
    // V^T fragments [dt][chunk]: lane holds V^T[16dt+ql][32c+8g .. +7]
    short8v vf[3][2];
    #pragma unroll
    for (int dt = 0; dt < 3; ++dt)
      #pragma unroll
      for (int c = 0; c < 2; ++c)
        vf[dt][c] = *reinterpret_cast<const short8v*>(
            vbase + (size_t)(16 * dt + ql) * 1024 + ki * 64 + 32 * c + 8 * g);

    // per q-tile: QK^T, mask, g-group-reduced online softmax, P -> LDS
    #pragma unroll
    for (int qt = 0; qt < 4; ++qt) {
      floatx4 s[4];
      #pragma unroll
      for (int kt = 0; kt < 4; ++kt) {
        s[kt] = __builtin_amdgcn_mfma_f32_16x16x32_bf16(
            kf[kt][0], qf[qt][0], (floatx4){0.f, 0.f, 0.f, 0.f}, 0, 0, 0);
        s[kt] = __builtin_amdgcn_mfma_f32_16x16x32_bf16(
            kf[kt][1], qf[qt][1], s[kt], 0, 0, 0);
      }
      const int qcol = qt * 16 + ql;
      float mt = -INFINITY;
      #pragma unroll
      for (int kt = 0; kt < 4; ++kt) {
        #pragma unroll
        for (int r = 0; r < 4; ++r) {
          const int delta = kt * 16 + 4 * g + r - qcol;
          const bool ok = (delta <= 5) && (delta >= -5);
          s[kt][r] = ok ? s[kt][r] : -INFINITY;
          mt = fmaxf(mt, s[kt][r]);
        }
      }
      // reduce max across the 4 lanes sharing this q (lane bits 4-5)
      mt = fmaxf(mt, __shfl_xor(mt, 16, 64));
      mt = fmaxf(mt, __shfl_xor(mt, 32, 64));
      const float mnew = fmaxf(mreg[qt], mt);  // finite: own column in window
      const float corr = __expf(mreg[qt] - mnew);
      mreg[qt] = mnew;
      float ps = 0.f;
      #pragma unroll
      for (int kt = 0; kt < 4; ++kt) {
        #pragma unroll
        for (int r = 0; r < 4; ++r) {
          const float p = __expf(s[kt][r] - mnew);  // masked -> exp(-inf)=0
          s[kt][r] = p;
          ps += p;
        }
      }
      // reduce sum across the g-group
      ps += __shfl_xor(ps, 16, 64);
      ps += __shfl_xor(ps, 32, 64);
      lreg[qt] = lreg[qt] * corr + ps;
      #pragma unroll
      for (int dt = 0; dt < 3; ++dt) {
        ot[dt][qt][0] *= corr; ot[dt][qt][1] *= corr;
        ot[dt][qt][2] *= corr; ot[dt][qt][3] *= corr;
      }
      // pack P (bf16), write C-layout rows: plds[q][kt*16 + 4g .. +3]
      #pragma unroll
      for (int kt = 0; kt < 4; ++kt) {
        uint2 pk;
        pk.x = (unsigned int)f2bu(s[kt][0]) | ((unsigned int)f2bu(s[kt][1]) << 16);
        pk.y = (unsigned int)f2bu(s[kt][2]) | ((unsigned int)f2bu(s[kt][3]) << 16);
        *reinterpret_cast<uint2*>(&plds[(qt * 16 + ql) * 72 + kt * 16 + 4 * g]) = pk;
      }
    }

    // PV: O^T[dt][qt] += V^T · P^T  (B-frag: lane reads plds[q][32c+8g .. +7])
    #pragma unroll
    for (int qt = 0; qt < 4; ++qt) {
      #pragma unroll
      for (int c = 0; c < 2; ++c) {
        const short8v pf = *reinterpret_cast<const short8v*>(
            &plds[(qt * 16 + ql) * 72 + 32 * c + 8 * g]);
        #pragma unroll
        for (int dt = 0; dt < 3; ++dt)
          ot[dt][qt] = __builtin_amdgcn_mfma_f32_16x16x32_bf16(
              vf[dt][c], pf, ot[dt][qt], 0, 0, 0);
      }
    }
  }

  // epilogue: normalize, store O^T -> attn_out[(b, i*64+q)][h*48 + d]
  const int b = bh >> 3, h = bh & 7;
  #pragma unroll
  for (int qt = 0; qt < 4; ++qt) {
    const float inv = 1.0f / lreg[qt];
    unsigned short* orow =
        attn_out + (size_t)(b * 1024 + i * 64 + qt * 16 + ql) * 384 + h * 48;
    #pragma unroll
    for (int dt = 0; dt < 3; ++dt) {
      const int d0 = 16 * dt + 4 * g;
      unsigned int w0 = (unsigned int)f2bu(ot[dt][qt][0] * inv) |
                        ((unsigned int)f2bu(ot[dt][qt][1] * inv) << 16);
      unsigned int w1 = (unsigned int)f2bu(ot[dt][qt][2] * inv) |
                        ((unsigned int)f2bu(ot[dt][qt][3] * inv) << 16);
      *reinterpret_cast<unsigned int*>(orow + d0)     = w0;
      *reinterpret_cast<unsigned int*>(orow + d0 + 2) = w1;
    }
  }
}

extern "C" void kernel_launch(void* const* d_in, const int* in_sizes, int n_in,
                              void* d_out, int out_size, void* d_ws, size_t ws_size,
                              hipStream_t stream) {
  const float* x      = (const float*)d_in[0];
  const float* w_qkv  = (const float*)d_in[1];
  const float* w_proj = (const float*)d_in[2];
  const float* b_proj = (const float*)d_in[3];
  // d_in[4] (mask) unused: window is analytic (|di|<=3, |dj|<=5)

  const size_t T = 25165824;  // 32768*384*2 bytes
  char* ws = (char*)d_ws;
  unsigned short* xb    = (unsigned short*)ws;            // aliased with attn_out
  unsigned short* qws   = (unsigned short*)(ws + T);
  unsigned short* kws   = (unsigned short*)(ws + 2 * T);
  unsigned short* vtws  = (unsigned short*)(ws + 3 * T);  // [bh][48][1024]
  unsigned short* wqkvT = (unsigned short*)(ws + 4 * T);
  unsigned short* wpT   = (unsigned short*)(ws + 4 * T + 884736);
  unsigned short* attn_out = xb;  // xb dead after K1
  float* out = (float*)d_out;

  // K0: conversions
  cvt_f32_bf16<<<12288, 256, 0, stream>>>((const float4*)x, (ushort4v*)xb, 3145728);
  transpose_cvt<<<dim3(36, 12), dim3(32, 8), 0, stream>>>(w_qkv, wqkvT, 384, 1152);
  transpose_cvt<<<dim3(12, 12), dim3(32, 8), 0, stream>>>(w_proj, wpT, 384, 384);

  // K1: qkv GEMM (M=32768, K=384, N=1152) -> q/k [bh][s][48], v^T [bh][48][s]
  gemm_mfma<0><<<dim3(9, 256), 256, 0, stream>>>(xb, wqkvT, nullptr, nullptr,
                                                 qws, kws, vtws);
  // K2: MFMA local attention -> attn_out bf16 [B*S, 384]
  attn_mfma<<<dim3(4096), 64, 0, stream>>>(qws, kws, vtws, attn_out);
  // K3: out = attn_out @ w_proj + bias (N=384), f32 out
  gemm_mfma<1><<<dim3(3, 256), 256, 0, stream>>>(attn_out, wpT, b_proj, out,
                                                 nullptr, nullptr, nullptr);
}

// Round 7
// 185.872 us; speedup vs baseline: 2.6958x; 1.0609x over previous
//
#include <hip/hip_runtime.h>
#include <hip/hip_bf16.h>

// Local-window attention, B=32 S=1024(16x64) H=8 D=384/8=48, window 7x11.
// R7: pipeline the GEMM K-loop (double-buffered LDS, prefetch-before-wait,
//     counted vmcnt(4), raw s_barrier) + chunked bijective XCD swizzle so the
//     n-blocks sharing an A-panel land on one XCD's L2.
//     attn_mfma / cvt / transpose unchanged from R6 (passing).

typedef __attribute__((ext_vector_type(8))) unsigned short ushort8;
typedef __attribute__((ext_vector_type(4))) unsigned short ushort4v;
typedef __attribute__((ext_vector_type(8))) short short8v;
typedef __attribute__((ext_vector_type(4))) float floatx4;

__device__ __forceinline__ float bf2f(unsigned short u) {
  union { unsigned int i; float f; } x;
  x.i = ((unsigned int)u) << 16;
  return x.f;
}

__device__ __forceinline__ unsigned short f2bu(float f) {
  union { float f; unsigned int i; } x;
  x.f = f;
  unsigned int lsb = (x.i >> 16) & 1u;
  x.i += 0x7FFFu + lsb;  // RNE
  return (unsigned short)(x.i >> 16);
}

__device__ __forceinline__ void gload_lds16(const void* g, void* l) {
  __builtin_amdgcn_global_load_lds(
      (const __attribute__((address_space(1))) unsigned int*)g,
      (__attribute__((address_space(3))) unsigned int*)l, 16, 0, 0);
}

// ---------------- K0a: f32 -> bf16 ----------------
__global__ __launch_bounds__(256) void cvt_f32_bf16(
    const float4* __restrict__ in, ushort4v* __restrict__ out, int n4) {
  const int i = blockIdx.x * 256 + threadIdx.x;
  if (i < n4) {
    const float4 v = in[i];
    ushort4v o;
    o[0] = f2bu(v.x); o[1] = f2bu(v.y); o[2] = f2bu(v.z); o[3] = f2bu(v.w);
    out[i] = o;
  }
}

// ---------------- K0b/c: transpose f32 [R][C] -> bf16 [C][R] ----------------
__global__ __launch_bounds__(256) void transpose_cvt(
    const float* __restrict__ in, unsigned short* __restrict__ out, int R, int C) {
  __shared__ float t[32][33];
  const int c0 = blockIdx.x * 32, r0 = blockIdx.y * 32;
  const int tx = threadIdx.x, ty = threadIdx.y;
  #pragma unroll
  for (int rr = ty; rr < 32; rr += 8) t[rr][tx] = in[(size_t)(r0 + rr) * C + c0 + tx];
  __syncthreads();
  #pragma unroll
  for (int rr = ty; rr < 32; rr += 8)
    out[(size_t)(c0 + rr) * R + r0 + tx] = f2bu(t[tx][rr]);
}

// ---------------- MFMA GEMM, 2-phase pipelined K-loop ----------------
// 128x128 tile, BK=32, dbuf LDS. Per iter: STAGE(next buf) -> vmcnt(4)
// (cur's 4 loads done, next's 4 stay in flight) -> s_barrier -> ds_read+MFMA
// -> lgkmcnt(0) -> s_barrier. XOR-16 swizzle both sides (R2-verified).
// Chunked XCD swizzle on flattened bid (nwg % 8 == 0 for both launches).
template <int MODE>
__global__ __launch_bounds__(256) void gemm_mfma(
    const unsigned short* __restrict__ A,   // [M][384] bf16
    const unsigned short* __restrict__ Bt,  // [N][384] bf16 (= B^T)
    const float* __restrict__ bias, float* __restrict__ outf,
    unsigned short* __restrict__ qws, unsigned short* __restrict__ kws,
    unsigned short* __restrict__ vtws)
{
  __shared__ unsigned short As[2][128 * 32];
  __shared__ unsigned short Bs[2][128 * 32];
  const int tid = threadIdx.x;
  const int lane = tid & 63, w = tid >> 6;
  const int wm = w & 1, wn = w >> 1;

  // chunked XCD swizzle: contiguous runs of nwg/8 blocks per XCD
  const int nbx = gridDim.x;
  const int nwg = nbx * gridDim.y;
  const int bid = blockIdx.y * nbx + blockIdx.x;
  const int swz = (bid & 7) * (nwg >> 3) + (bid >> 3);
  const int n0 = (swz % nbx) * 128;
  const int m0 = (swz / nbx) * 128;

  floatx4 acc[4][4];
  #pragma unroll
  for (int mi = 0; mi < 4; ++mi)
    #pragma unroll
    for (int ni = 0; ni < 4; ++ni)
      acc[mi][ni] = (floatx4){0.f, 0.f, 0.f, 0.f};

  const int srow = w * 16 + (lane >> 2);
  const int kslot16 = (lane & 3) * 16;

  auto STAGE = [&](int buf, int k0) {
    #pragma unroll
    for (int c = 0; c < 2; ++c) {
      const int r = c * 64 + srow;
      const int kb = kslot16 ^ ((r & 3) << 4);
      gload_lds16((const char*)A + (size_t)(m0 + r) * 768 + k0 * 2 + kb,
                  (char*)As[buf] + c * 4096 + w * 1024);
      gload_lds16((const char*)Bt + (size_t)(n0 + r) * 768 + k0 * 2 + kb,
                  (char*)Bs[buf] + c * 4096 + w * 1024);
    }
  };

  STAGE(0, 0);
  int cur = 0;

  for (int k0 = 0; k0 < 384; k0 += 32) {
    if (k0 + 32 < 384) {
      STAGE(cur ^ 1, k0 + 32);                       // prefetch next tile
      asm volatile("s_waitcnt vmcnt(4)" ::: "memory");  // cur's loads done
    } else {
      asm volatile("s_waitcnt vmcnt(0)" ::: "memory");
    }
    __builtin_amdgcn_s_barrier();                    // cur tile visible to all

    short8v a[4], b[4];
    const int kgb = (lane >> 4) * 16;
    #pragma unroll
    for (int mi = 0; mi < 4; ++mi) {
      const int r = wm * 64 + mi * 16 + (lane & 15);
      a[mi] = *reinterpret_cast<const short8v*>(
          (const char*)As[cur] + r * 64 + (kgb ^ ((r & 3) << 4)));
    }
    #pragma unroll
    for (int ni = 0; ni < 4; ++ni) {
      const int r = wn * 64 + ni * 16 + (lane & 15);
      b[ni] = *reinterpret_cast<const short8v*>(
          (const char*)Bs[cur] + r * 64 + (kgb ^ ((r & 3) << 4)));
    }
    #pragma unroll
    for (int mi = 0; mi < 4; ++mi)
      #pragma unroll
      for (int ni = 0; ni < 4; ++ni)
        acc[mi][ni] = __builtin_amdgcn_mfma_f32_16x16x32_bf16(
            a[mi], b[ni], acc[mi][ni], 0, 0, 0);

    asm volatile("s_waitcnt lgkmcnt(0)" ::: "memory");  // ds_reads drained
    __builtin_amdgcn_s_barrier();                       // safe to overwrite cur
    cur ^= 1;
  }

  const int col_l = lane & 15;
  const int row_l = (lane >> 4) * 4;

  if (MODE == 0) {
    const float QSCALE = 0.14433756729740643f;  // 1/sqrt(48)
    #pragma unroll
    for (int ni = 0; ni < 4; ++ni) {
      const int cg = n0 + wn * 64 + ni * 16 + col_l;
      const int which = cg / 384;
      const int rem = cg - which * 384;
      const int h = rem / 48;
      const int d = rem - h * 48;
      const float scale = (which == 0) ? QSCALE : 1.f;
      #pragma unroll
      for (int mi = 0; mi < 4; ++mi) {
        #pragma unroll
        for (int reg = 0; reg < 4; ++reg) {
          const int r = m0 + wm * 64 + mi * 16 + row_l + reg;
          const int bb = r >> 10, s = r & 1023;
          const unsigned short val = f2bu(acc[mi][ni][reg] * scale);
          if (which == 0)
            qws[(((size_t)(bb * 8 + h)) * 1024 + s) * 48 + d] = val;
          else if (which == 1)
            kws[(((size_t)(bb * 8 + h)) * 1024 + s) * 48 + d] = val;
          else  // V stored TRANSPOSED: vt[bh][d][s]
            vtws[(((size_t)(bb * 8 + h)) * 48 + d) * 1024 + s] = val;
        }
      }
    }
  } else {
    #pragma unroll
    for (int ni = 0; ni < 4; ++ni) {
      const int cg = n0 + wn * 64 + ni * 16 + col_l;
      const float bv = bias[cg];
      #pragma unroll
      for (int mi = 0; mi < 4; ++mi) {
        #pragma unroll
        for (int reg = 0; reg < 4; ++reg) {
          const int r = m0 + wm * 64 + mi * 16 + row_l + reg;
          outf[(size_t)r * 384 + cg] = acc[mi][ni][reg] + bv;
        }
      }
    }
  }
}

// ---------------- K2: MFMA local attention (unchanged from R6) ----------------
__global__ __launch_bounds__(64) void attn_mfma(
    const unsigned short* __restrict__ qws,  // [bh][1024][48]
    const unsigned short* __restrict__ kws,  // [bh][1024][48]
    const unsigned short* __restrict__ vt,   // [bh][48][1024]
    unsigned short* __restrict__ attn_out)   // [b*1024][384] bf16
{
  __shared__ unsigned short plds[64 * 72];  // stride 144B: 16B-aligned rows

  const int task = ((blockIdx.x & 7) << 9) | (blockIdx.x >> 3);  // 4096%8==0
  const int i  = task & 15;
  const int bh = task >> 4;
  const int lane = threadIdx.x;
  const int ql = lane & 15;   // q local (also A-frag row local)
  const int g  = lane >> 4;   // 8-elem k-slice group

  const unsigned short* qbase = qws + (size_t)bh * 1024 * 48;
  const unsigned short* kbase = kws + (size_t)bh * 1024 * 48;
  const unsigned short* vbase = vt  + (size_t)bh * 48 * 1024;

  const short8v zfrag = (short8v){0, 0, 0, 0, 0, 0, 0, 0};

  // Q fragments [qt][kstep]; D=48 zero-padded to 64 (kstep1, g>=2 -> 0)
  short8v qf[4][2];
  #pragma unroll
  for (int qt = 0; qt < 4; ++qt) {
    const unsigned short* qrow = qbase + (size_t)(i * 64 + qt * 16 + ql) * 48;
    qf[qt][0] = *reinterpret_cast<const short8v*>(qrow + 8 * g);
    qf[qt][1] = (g < 2) ? *reinterpret_cast<const short8v*>(qrow + 32 + 8 * g)
                        : zfrag;
  }

  floatx4 ot[3][4];  // O^T accum [dtile][qtile], d = 16dt+4g+reg, q = qt*16+ql
  #pragma unroll
  for (int dt = 0; dt < 3; ++dt)
    #pragma unroll
    for (int qt = 0; qt < 4; ++qt)
      ot[dt][qt] = (floatx4){0.f, 0.f, 0.f, 0.f};
  float mreg[4] = {-INFINITY, -INFINITY, -INFINITY, -INFINITY};
  float lreg[4] = {0.f, 0.f, 0.f, 0.f};

  const int ki0 = (i - 3 < 0) ? 0 : i - 3;
  const int ki1 = (i + 3 > 15) ? 15 : i + 3;

  for (int ki = ki0; ki <= ki1; ++ki) {
    // K fragments [kt][kstep]
    short8v kf[4][2];
    #pragma unroll
    for (int kt = 0; kt < 4; ++kt) {
      const unsigned short* krow = kbase + (size_t)(ki * 64 + kt * 16 + ql) * 48;
      kf[kt][0] = *reinterpret_cast<const short8v*>(krow + 8 * g);
      kf[kt][1] = (g < 2) ? *reinterpret_cast<const short8v*>(krow + 32 + 8 * g)
                          : zfrag;
    }
    // V^T fragments [dt][chunk]: lane holds V^T[16dt+ql][32c+8g .. +7]
    short8v vf[3][2];
    #pragma unroll
    for (int dt = 0; dt < 3; ++dt)
      #pragma unroll
      for (int c = 0; c < 2; ++c)
        vf[dt][c] = *reinterpret_cast<const short8v*>(
            vbase + (size_t)(16 * dt + ql) * 1024 + ki * 64 + 32 * c + 8 * g);

    // per q-tile: QK^T, mask, g-group-reduced online softmax, P -> LDS
    #pragma unroll
    for (int qt = 0; qt < 4; ++qt) {
      floatx4 s[4];
      #pragma unroll
      for (int kt = 0; kt < 4; ++kt) {
        s[kt] = __builtin_amdgcn_mfma_f32_16x16x32_bf16(
            kf[kt][0], qf[qt][0], (floatx4){0.f, 0.f, 0.f, 0.f}, 0, 0, 0);
        s[kt] = __builtin_amdgcn_mfma_f32_16x16x32_bf16(
            kf[kt][1], qf[qt][1], s[kt], 0, 0, 0);
      }
      const int qcol = qt * 16 + ql;
      float mt = -INFINITY;
      #pragma unroll
      for (int kt = 0; kt < 4; ++kt) {
        #pragma unroll
        for (int r = 0; r < 4; ++r) {
          const int delta = kt * 16 + 4 * g + r - qcol;
          const bool ok = (delta <= 5) && (delta >= -5);
          s[kt][r] = ok ? s[kt][r] : -INFINITY;
          mt = fmaxf(mt, s[kt][r]);
        }
      }
      // reduce max across the 4 lanes sharing this q (lane bits 4-5)
      mt = fmaxf(mt, __shfl_xor(mt, 16, 64));
      mt = fmaxf(mt, __shfl_xor(mt, 32, 64));
      const float mnew = fmaxf(mreg[qt], mt);  // finite: own column in window
      const float corr = __expf(mreg[qt] - mnew);
      mreg[qt] = mnew;
      float ps = 0.f;
      #pragma unroll
      for (int kt = 0; kt < 4; ++kt) {
        #pragma unroll
        for (int r = 0; r < 4; ++r) {
          const float p = __expf(s[kt][r] - mnew);  // masked -> exp(-inf)=0
          s[kt][r] = p;
          ps += p;
        }
      }
      // reduce sum across the g-group
      ps += __shfl_xor(ps, 16, 64);
      ps += __shfl_xor(ps, 32, 64);
      lreg[qt] = lreg[qt] * corr + ps;
      #pragma unroll
      for (int dt = 0; dt < 3; ++dt) {
        ot[dt][qt][0] *= corr; ot[dt][qt][1] *= corr;
        ot[dt][qt][2] *= corr; ot[dt][qt][3] *= corr;
      }
      // pack P (bf16), write C-layout rows: plds[q][kt*16 + 4g .. +3]
      #pragma unroll
      for (int kt = 0; kt < 4; ++kt) {
        uint2 pk;
        pk.x = (unsigned int)f2bu(s[kt][0]) | ((unsigned int)f2bu(s[kt][1]) << 16);
        pk.y = (unsigned int)f2bu(s[kt][2]) | ((unsigned int)f2bu(s[kt][3]) << 16);
        *reinterpret_cast<uint2*>(&plds[(qt * 16 + ql) * 72 + kt * 16 + 4 * g]) = pk;
      }
    }

    // PV: O^T[dt][qt] += V^T · P^T  (B-frag: lane reads plds[q][32c+8g .. +7])
    #pragma unroll
    for (int qt = 0; qt < 4; ++qt) {
      #pragma unroll
      for (int c = 0; c < 2; ++c) {
        const short8v pf = *reinterpret_cast<const short8v*>(
            &plds[(qt * 16 + ql) * 72 + 32 * c + 8 * g]);
        #pragma unroll
        for (int dt = 0; dt < 3; ++dt)
          ot[dt][qt] = __builtin_amdgcn_mfma_f32_16x16x32_bf16(
              vf[dt][c], pf, ot[dt][qt], 0, 0, 0);
      }
    }
  }

  // epilogue: normalize, store O^T -> attn_out[(b, i*64+q)][h*48 + d]
  const int b = bh >> 3, h = bh & 7;
  #pragma unroll
  for (int qt = 0; qt < 4; ++qt) {
    const float inv = 1.0f / lreg[qt];
    unsigned short* orow =
        attn_out + (size_t)(b * 1024 + i * 64 + qt * 16 + ql) * 384 + h * 48;
    #pragma unroll
    for (int dt = 0; dt < 3; ++dt) {
      const int d0 = 16 * dt + 4 * g;
      unsigned int w0 = (unsigned int)f2bu(ot[dt][qt][0] * inv) |
                        ((unsigned int)f2bu(ot[dt][qt][1] * inv) << 16);
      unsigned int w1 = (unsigned int)f2bu(ot[dt][qt][2] * inv) |
                        ((unsigned int)f2bu(ot[dt][qt][3] * inv) << 16);
      *reinterpret_cast<unsigned int*>(orow + d0)     = w0;
      *reinterpret_cast<unsigned int*>(orow + d0 + 2) = w1;
    }
  }
}

extern "C" void kernel_launch(void* const* d_in, const int* in_sizes, int n_in,
                              void* d_out, int out_size, void* d_ws, size_t ws_size,
                              hipStream_t stream) {
  const float* x      = (const float*)d_in[0];
  const float* w_qkv  = (const float*)d_in[1];
  const float* w_proj = (const float*)d_in[2];
  const float* b_proj = (const float*)d_in[3];
  // d_in[4] (mask) unused: window is analytic (|di|<=3, |dj|<=5)

  const size_t T = 25165824;  // 32768*384*2 bytes
  char* ws = (char*)d_ws;
  unsigned short* xb    = (unsigned short*)ws;            // aliased with attn_out
  unsigned short* qws   = (unsigned short*)(ws + T);
  unsigned short* kws   = (unsigned short*)(ws + 2 * T);
  unsigned short* vtws  = (unsigned short*)(ws + 3 * T);  // [bh][48][1024]
  unsigned short* wqkvT = (unsigned short*)(ws + 4 * T);
  unsigned short* wpT   = (unsigned short*)(ws + 4 * T + 884736);
  unsigned short* attn_out = xb;  // xb dead after K1
  float* out = (float*)d_out;

  // K0: conversions
  cvt_f32_bf16<<<12288, 256, 0, stream>>>((const float4*)x, (ushort4v*)xb, 3145728);
  transpose_cvt<<<dim3(36, 12), dim3(32, 8), 0, stream>>>(w_qkv, wqkvT, 384, 1152);
  transpose_cvt<<<dim3(12, 12), dim3(32, 8), 0, stream>>>(w_proj, wpT, 384, 384);

  // K1: qkv GEMM (M=32768, K=384, N=1152) -> q/k [bh][s][48], v^T [bh][48][s]
  gemm_mfma<0><<<dim3(9, 256), 256, 0, stream>>>(xb, wqkvT, nullptr, nullptr,
                                                 qws, kws, vtws);
  // K2: MFMA local attention -> attn_out bf16 [B*S, 384]
  attn_mfma<<<dim3(4096), 64, 0, stream>>>(qws, kws, vtws, attn_out);
  // K3: out = attn_out @ w_proj + bias (N=384), f32 out
  gemm_mfma<1><<<dim3(3, 256), 256, 0, stream>>>(attn_out, wpT, b_proj, out,
                                                 nullptr, nullptr, nullptr);
}